// Round 1
// baseline (929.607 us; speedup 1.0000x reference)
//
#include <hip/hip_runtime.h>
#include <cmath>

#define HW_ 16384

__device__ __forceinline__ unsigned f2key(float f){
    unsigned u = __float_as_uint(f);
    return u ^ ((u & 0x80000000u) ? 0xFFFFFFFFu : 0x80000000u);
}
__device__ __forceinline__ float key2f(unsigned k){
    unsigned u = (k & 0x80000000u) ? (k ^ 0x80000000u) : ~k;
    return __uint_as_float(u);
}

#define SEL_CAP 1024

__device__ __forceinline__ void reduce_maxmin(unsigned locA, unsigned locB, int tid,
        unsigned* redA, unsigned* redB, unsigned* s_keyA, unsigned* s_keyB)
{
    #pragma unroll
    for (int o = 32; o > 0; o >>= 1){
        locA = max(locA, __shfl_down(locA, o));
        locB = min(locB, __shfl_down(locB, o));
    }
    if ((tid & 63) == 0){ redA[tid >> 6] = locA; redB[tid >> 6] = locB; }
    __syncthreads();
    if (tid == 0){
        unsigned a = redA[0], b = redB[0];
        for (int w = 1; w < 4; ++w){ a = max(a, redA[w]); b = min(b, redB[w]); }
        *s_keyA = a; *s_keyB = b;
    }
    __syncthreads();
}

// K1: per (b,c) channel. quantile -> mask -> c0, a1=0.99*pool3(c0),
// out_partial=max(c0,a1), d1=g1*pool5s2(a1) on 64x64 grid.
__global__ __launch_bounds__(256) void k1_prop(
    const float* __restrict__ x, float* __restrict__ outp,
    float* __restrict__ d1g, float g1)
{
    __shared__ __align__(16) float X[16384];
    __shared__ __align__(16) float A[16384];
    __shared__ unsigned hist[4096];
    __shared__ unsigned cand[SEL_CAP];
    __shared__ unsigned spart[256];
    __shared__ unsigned redA[4], redB[4];
    __shared__ unsigned s_cnt, s_dA, s_dB, s_cloA, s_cloB, s_keyA, s_keyB;

    const int tid = threadIdx.x;
    const unsigned bc = blockIdx.x;
    const float* xp = x + (size_t)bc * HW_;

    #pragma unroll
    for (int k = 0; k < 16; ++k) hist[tid + k * 256] = 0u;
    if (tid == 0) s_cnt = 0u;
    __syncthreads();

    // load x channel into LDS + 12-bit (bits 31..20) histogram
    {
        const float4* xp4 = (const float4*)xp;
        #pragma unroll
        for (int k = 0; k < 16; ++k){
            float4 v = xp4[tid + k * 256];
            ((float4*)X)[tid + k * 256] = v;
            atomicAdd(&hist[f2key(v.x) >> 20], 1u);
            atomicAdd(&hist[f2key(v.y) >> 20], 1u);
            atomicAdd(&hist[f2key(v.z) >> 20], 1u);
            atomicAdd(&hist[f2key(v.w) >> 20], 1u);
        }
    }
    __syncthreads();

    unsigned rA = 15563u, rB = 15564u;     // ascending ranks (0-based)
    unsigned prefVal = 0u, prefMask = 0u;
    bool done = false;

    // ---- level 0: 12-bit ----
    {
        unsigned part = 0u;
        #pragma unroll
        for (int k = 0; k < 16; ++k) part += hist[tid * 16 + k];
        spart[tid] = part;
        __syncthreads();
        for (int off = 1; off < 256; off <<= 1){
            unsigned v = (tid >= off) ? spart[tid - off] : 0u;
            __syncthreads();
            spart[tid] += v;
            __syncthreads();
        }
        unsigned plo = (tid == 0) ? 0u : spart[tid - 1];
        unsigned phi = spart[tid];
        if (rA >= plo && rA < phi){
            unsigned c = plo;
            for (int k = 0; k < 16; ++k){
                unsigned hh = hist[tid * 16 + k];
                if (rA < c + hh){ s_dA = tid * 16 + k; s_cloA = c; break; }
                c += hh;
            }
        }
        if (rB >= plo && rB < phi){
            unsigned c = plo;
            for (int k = 0; k < 16; ++k){
                unsigned hh = hist[tid * 16 + k];
                if (rB < c + hh){ s_dB = tid * 16 + k; s_cloB = c; break; }
                c += hh;
            }
        }
        __syncthreads();
        unsigned dA = s_dA, dB = s_dB;
        if (dA != dB){
            unsigned locA = 0u, locB = 0xFFFFFFFFu;
            #pragma unroll 8
            for (int k = 0; k < 64; ++k){
                unsigned key = f2key(X[tid + k * 256]);
                unsigned d = key >> 20;
                if (d == dA) locA = max(locA, key);
                if (d == dB) locB = min(locB, key);
            }
            reduce_maxmin(locA, locB, tid, redA, redB, &s_keyA, &s_keyB);
            done = true;
        } else {
            prefVal = dA << 20; prefMask = 0xFFFu << 20;
            rA -= s_cloA; rB -= s_cloB;
            #pragma unroll 8
            for (int k = 0; k < 64; ++k){
                unsigned key = f2key(X[tid + k * 256]);
                if ((key >> 20) == dA){
                    unsigned id2 = atomicAdd(&s_cnt, 1u);
                    if (id2 < SEL_CAP) cand[id2] = key;
                }
            }
            __syncthreads();
        }
    }

    // ---- levels 1..3: 8,8,4 bits ----
    if (!done){
        unsigned nc = s_cnt;
        bool useCand = (nc <= SEL_CAP);
        const int shifts[3] = {12, 4, 0};
        const int bitsv[3]  = {8, 8, 4};
        for (int lvl = 0; lvl < 3 && !done; ++lvl){
            int shift = shifts[lvl];
            unsigned nb = 1u << bitsv[lvl];
            unsigned msk = nb - 1u;
            if (tid < (int)nb) hist[tid] = 0u;
            __syncthreads();
            if (useCand){
                for (unsigned i = tid; i < nc; i += 256){
                    unsigned key = cand[i];
                    if ((key & prefMask) == prefVal)
                        atomicAdd(&hist[(key >> shift) & msk], 1u);
                }
            } else {
                #pragma unroll 8
                for (int k = 0; k < 64; ++k){
                    unsigned key = f2key(X[tid + k * 256]);
                    if ((key & prefMask) == prefVal)
                        atomicAdd(&hist[(key >> shift) & msk], 1u);
                }
            }
            __syncthreads();
            spart[tid] = (tid < (int)nb) ? hist[tid] : 0u;
            __syncthreads();
            for (int off = 1; off < 256; off <<= 1){
                unsigned v = (tid >= off) ? spart[tid - off] : 0u;
                __syncthreads();
                spart[tid] += v;
                __syncthreads();
            }
            unsigned plo = (tid == 0) ? 0u : spart[tid - 1];
            unsigned phi = spart[tid];
            if (tid < (int)nb){
                if (rA >= plo && rA < phi){ s_dA = tid; s_cloA = plo; }
                if (rB >= plo && rB < phi){ s_dB = tid; s_cloB = plo; }
            }
            __syncthreads();
            unsigned dA = s_dA, dB = s_dB;
            if (dA != dB){
                unsigned mA = prefMask | (msk << shift);
                unsigned vAp = prefVal | (dA << shift);
                unsigned vBp = prefVal | (dB << shift);
                unsigned locA = 0u, locB = 0xFFFFFFFFu;
                if (useCand){
                    for (unsigned i = tid; i < nc; i += 256){
                        unsigned key = cand[i];
                        if ((key & mA) == vAp) locA = max(locA, key);
                        if ((key & mA) == vBp) locB = min(locB, key);
                    }
                } else {
                    #pragma unroll 8
                    for (int k = 0; k < 64; ++k){
                        unsigned key = f2key(X[tid + k * 256]);
                        if ((key & mA) == vAp) locA = max(locA, key);
                        if ((key & mA) == vBp) locB = min(locB, key);
                    }
                }
                reduce_maxmin(locA, locB, tid, redA, redB, &s_keyA, &s_keyB);
                done = true;
            } else {
                prefVal |= dA << shift;
                prefMask |= msk << shift;
                rA -= s_cloA; rB -= s_cloB;
                if (lvl == 2){
                    if (tid == 0){ s_keyA = prefVal; s_keyB = prefVal; }
                    done = true;
                }
                __syncthreads();
            }
        }
    }

    // threshold, replicating jnp.quantile f32 interpolation
    float vlo = key2f(s_keyA);
    float vhi = key2f(s_keyB);
    float idxq = 0.95f * 16383.0f;
    float frac = idxq - floorf(idxq);
    float thr = vlo * (1.0f - frac) + vhi * frac;

    // mask -> c0 (in place)
    #pragma unroll 8
    for (int k = 0; k < 64; ++k){
        int p = tid + k * 256;
        float v = X[p];
        X[p] = (v >= thr) ? v : 0.0f;
    }
    __syncthreads();

    // horizontal rowmax3 -> A
    #pragma unroll 8
    for (int k = 0; k < 64; ++k){
        int p = tid + k * 256;
        int j = p & 127;
        float m = X[p];
        if (j > 0)   m = fmaxf(m, X[p - 1]);
        if (j < 127) m = fmaxf(m, X[p + 1]);
        A[p] = m;
    }
    __syncthreads();

    // vertical: a1 = 0.99*colmax3(A); out = max(c0,a1); X <- a1
    float* op = outp + (size_t)bc * HW_;
    #pragma unroll 8
    for (int k = 0; k < 64; ++k){
        int p = tid + k * 256;
        int r = p >> 7;
        float m = A[p];
        if (r > 0)   m = fmaxf(m, A[p - 128]);
        if (r < 127) m = fmaxf(m, A[p + 128]);
        float a1 = 0.99f * m;
        float c0 = X[p];
        op[p] = fmaxf(c0, a1);
        X[p] = a1;
    }
    __syncthreads();

    // H5: horizontal 5-tap at even centers over a1 (in X) -> A[r*64+i]
    #pragma unroll 8
    for (int k = 0; k < 32; ++k){
        int p = tid + k * 256;        // 8192
        int r = p >> 6;
        int i = p & 63;
        int c = 2 * i;
        const float* row = X + r * 128;
        float m = fmaxf(row[c], row[c + 1]);
        if (c >= 1) m = fmaxf(m, row[c - 1]);
        if (c >= 2) m = fmaxf(m, row[c - 2]);
        if (c + 2 <= 127) m = fmaxf(m, row[c + 2]);
        A[p] = m;
    }
    __syncthreads();

    // vertical 5-tap stride2 + scale -> d1 (64x64)
    float* dp = d1g + (size_t)bc * 4096;
    #pragma unroll 4
    for (int k = 0; k < 16; ++k){
        int p = tid + k * 256;        // 4096
        int i = p >> 6;
        int j = p & 63;
        int r = 2 * i;
        float m = fmaxf(A[r * 64 + j], A[(r + 1) * 64 + j]);
        if (r >= 1) m = fmaxf(m, A[(r - 1) * 64 + j]);
        if (r >= 2) m = fmaxf(m, A[(r - 2) * 64 + j]);
        if (r + 2 <= 127) m = fmaxf(m, A[(r + 2) * 64 + j]);
        dp[p] = g1 * m;
    }
}

// K2: 64x64 chain d2..d5, m64 = max(d1..d5), in-place over d1 buffer
__global__ __launch_bounds__(256) void k2_chain(
    float* __restrict__ dm, float g2, float g3, float g4, float g5)
{
    __shared__ __align__(16) float D[4096];
    __shared__ __align__(16) float T[4096];
    __shared__ __align__(16) float M[4096];
    const int tid = threadIdx.x;
    const unsigned bc = blockIdx.x;
    float* p = dm + (size_t)bc * 4096;
    const float4* p4 = (const float4*)p;
    #pragma unroll
    for (int k = 0; k < 4; ++k){
        float4 v = p4[tid + k * 256];
        ((float4*)D)[tid + k * 256] = v;
        ((float4*)M)[tid + k * 256] = v;
    }
    __syncthreads();
    const float gs[4] = {g2, g3, g4, g5};
    for (int it = 0; it < 4; ++it){
        float g = gs[it];
        #pragma unroll 4
        for (int k = 0; k < 16; ++k){
            int q = tid + k * 256;
            int j = q & 63;
            float m = D[q];
            if (j > 0)  m = fmaxf(m, D[q - 1]);
            if (j < 63) m = fmaxf(m, D[q + 1]);
            T[q] = m;
        }
        __syncthreads();
        #pragma unroll 4
        for (int k = 0; k < 16; ++k){
            int q = tid + k * 256;
            int r = q >> 6;
            float m = T[q];
            if (r > 0)  m = fmaxf(m, T[q - 64]);
            if (r < 63) m = fmaxf(m, T[q + 64]);
            float v = g * m;
            D[q] = v;
            M[q] = fmaxf(M[q], v);
        }
        __syncthreads();
    }
    #pragma unroll
    for (int k = 0; k < 4; ++k)
        ((float4*)p)[tid + k * 256] = ((float4*)M)[tid + k * 256];
}

// K3: fused  out' = max(outp, up(m64)) -> h = relu(W1 out'+b1) ->
//            R = sigmoid(W2 h + b2) -> y = x*R
// one block per (b, 2-row tile): 16*64 = 1024 blocks, 256 px each
__global__ __launch_bounds__(256) void k3_mlp(
    const float* __restrict__ x, const float* __restrict__ outp,
    const float* __restrict__ m64,
    const float* __restrict__ w1, const float* __restrict__ b1,
    const float* __restrict__ w2, const float* __restrict__ b2,
    float* __restrict__ y)
{
    __shared__ __align__(16) float W1s[256 * 16];  // [c][m]
    __shared__ __align__(16) float W2s[256 * 16];  // [c][m]
    __shared__ float B1s[16];
    __shared__ float B2s[256];
    const int tid = threadIdx.x;
    const int blk = blockIdx.x;
    const int b = blk >> 6;
    const int t = blk & 63;

    for (int q = tid; q < 4096; q += 256){
        int c = q >> 4, m = q & 15;
        W1s[q] = w1[m * 256 + c];
        W2s[q] = w2[q];
    }
    if (tid < 16) B1s[tid] = b1[tid];
    B2s[tid] = b2[tid];
    __syncthreads();

    const int pix = t * 256 + tid;
    const int mi = (pix >> 8) * 64 + ((pix & 127) >> 1);
    const size_t base = (size_t)b * 256 * HW_;
    const size_t mbase = (size_t)b * 256 * 4096;

    float h[16];
    #pragma unroll
    for (int m = 0; m < 16; ++m) h[m] = 0.0f;

    #pragma unroll 4
    for (int c = 0; c < 256; ++c){
        float o  = outp[base + (size_t)c * HW_ + pix];
        float mo = m64[mbase + (size_t)c * 4096 + mi];
        o = fmaxf(o, mo);
        const float4* wr = (const float4*)&W1s[c * 16];
        float4 a0 = wr[0], a1 = wr[1], a2 = wr[2], a3 = wr[3];
        h[0]  = fmaf(a0.x, o, h[0]);  h[1]  = fmaf(a0.y, o, h[1]);
        h[2]  = fmaf(a0.z, o, h[2]);  h[3]  = fmaf(a0.w, o, h[3]);
        h[4]  = fmaf(a1.x, o, h[4]);  h[5]  = fmaf(a1.y, o, h[5]);
        h[6]  = fmaf(a1.z, o, h[6]);  h[7]  = fmaf(a1.w, o, h[7]);
        h[8]  = fmaf(a2.x, o, h[8]);  h[9]  = fmaf(a2.y, o, h[9]);
        h[10] = fmaf(a2.z, o, h[10]); h[11] = fmaf(a2.w, o, h[11]);
        h[12] = fmaf(a3.x, o, h[12]); h[13] = fmaf(a3.y, o, h[13]);
        h[14] = fmaf(a3.z, o, h[14]); h[15] = fmaf(a3.w, o, h[15]);
    }
    #pragma unroll
    for (int m = 0; m < 16; ++m) h[m] = fmaxf(h[m] + B1s[m], 0.0f);

    #pragma unroll 4
    for (int c = 0; c < 256; ++c){
        const float4* wr = (const float4*)&W2s[c * 16];
        float4 a0 = wr[0], a1 = wr[1], a2 = wr[2], a3 = wr[3];
        float acc = B2s[c];
        acc += a0.x * h[0]  + a0.y * h[1]  + a0.z * h[2]  + a0.w * h[3];
        acc += a1.x * h[4]  + a1.y * h[5]  + a1.z * h[6]  + a1.w * h[7];
        acc += a2.x * h[8]  + a2.y * h[9]  + a2.z * h[10] + a2.w * h[11];
        acc += a3.x * h[12] + a3.y * h[13] + a3.z * h[14] + a3.w * h[15];
        float R = 1.0f / (1.0f + __expf(-acc));
        float xv = x[base + (size_t)c * HW_ + pix];
        y[base + (size_t)c * HW_ + pix] = xv * R;
    }
}

extern "C" void kernel_launch(void* const* d_in, const int* in_sizes, int n_in,
                              void* d_out, int out_size, void* d_ws, size_t ws_size,
                              hipStream_t stream) {
    const float* x  = (const float*)d_in[0];
    const float* w1 = (const float*)d_in[1];
    const float* b1 = (const float*)d_in[2];
    const float* w2 = (const float*)d_in[3];
    const float* b2 = (const float*)d_in[4];
    float* y  = (float*)d_out;
    float* ws = (float*)d_ws;

    float* outp = ws;                     // 67108864 floats (268 MB)
    float* d1   = ws + 67108864;          // 16777216 floats (67 MB), reused as m64

    float g[6];
    for (int i = 0; i < 6; ++i) g[i] = (float)std::pow(0.99, (double)(1 << i));

    k1_prop<<<4096, 256, 0, stream>>>(x, outp, d1, g[1]);
    k2_chain<<<4096, 256, 0, stream>>>(d1, g[2], g[3], g[4], g[5]);
    k3_mlp<<<1024, 256, 0, stream>>>(x, outp, d1, w1, b1, w2, b2, y);
}

// Round 2
// 556.670 us; speedup vs baseline: 1.6699x; 1.6699x over previous
//
#include <hip/hip_runtime.h>
#include <cmath>
#include <cfloat>

#define HW_ 16384

__device__ __forceinline__ unsigned f2key(float f){
    unsigned u = __float_as_uint(f);
    return u ^ ((u & 0x80000000u) ? 0xFFFFFFFFu : 0x80000000u);
}
__device__ __forceinline__ float key2f(unsigned k){
    unsigned u = (k & 0x80000000u) ? (k ^ 0x80000000u) : ~k;
    return __uint_as_float(u);
}

#define SEL_CAP 1024

__device__ __forceinline__ void reduce_maxmin(unsigned locA, unsigned locB, int tid,
        unsigned* redA, unsigned* redB, unsigned* s_keyA, unsigned* s_keyB)
{
    #pragma unroll
    for (int o = 32; o > 0; o >>= 1){
        locA = max(locA, __shfl_down(locA, o));
        locB = min(locB, __shfl_down(locB, o));
    }
    if ((tid & 63) == 0){ redA[tid >> 6] = locA; redB[tid >> 6] = locB; }
    __syncthreads();
    if (tid == 0){
        unsigned a = redA[0], b = redB[0];
        for (int w = 1; w < 4; ++w){ a = max(a, redA[w]); b = min(b, redB[w]); }
        *s_keyA = a; *s_keyB = b;
    }
    __syncthreads();
}

// K1a: per (b,c) channel quantile threshold via dual-rank radix select.
// Reads x from global (channel = 64KB, refinement passes hit L2).
// LDS ~21KB -> high occupancy.
__global__ __launch_bounds__(256) void k1a_thr(
    const float* __restrict__ x, float* __restrict__ throut)
{
    __shared__ unsigned hist[4096];
    __shared__ unsigned cand[SEL_CAP];
    __shared__ unsigned spart[256];
    __shared__ unsigned redA[4], redB[4];
    __shared__ unsigned s_cnt, s_dA, s_dB, s_cloA, s_cloB, s_keyA, s_keyB;

    const int tid = threadIdx.x;
    const unsigned bc = blockIdx.x;
    const float4* xp4 = (const float4*)(x + (size_t)bc * HW_);

    #pragma unroll
    for (int k = 0; k < 16; ++k) hist[tid + k * 256] = 0u;
    if (tid == 0) s_cnt = 0u;
    __syncthreads();

    // pass 1: 12-bit histogram (bits 31..20 of monotone key)
    #pragma unroll 4
    for (int k = 0; k < 16; ++k){
        float4 v = xp4[tid + k * 256];
        atomicAdd(&hist[f2key(v.x) >> 20], 1u);
        atomicAdd(&hist[f2key(v.y) >> 20], 1u);
        atomicAdd(&hist[f2key(v.z) >> 20], 1u);
        atomicAdd(&hist[f2key(v.w) >> 20], 1u);
    }
    __syncthreads();

    unsigned rA = 15563u, rB = 15564u;     // ascending ranks (0-based)
    unsigned prefVal = 0u, prefMask = 0u;
    bool done = false;

    // ---- level 0: 12-bit ----
    {
        unsigned part = 0u;
        #pragma unroll
        for (int k = 0; k < 16; ++k) part += hist[tid * 16 + k];
        spart[tid] = part;
        __syncthreads();
        for (int off = 1; off < 256; off <<= 1){
            unsigned v = (tid >= off) ? spart[tid - off] : 0u;
            __syncthreads();
            spart[tid] += v;
            __syncthreads();
        }
        unsigned plo = (tid == 0) ? 0u : spart[tid - 1];
        unsigned phi = spart[tid];
        if (rA >= plo && rA < phi){
            unsigned c = plo;
            for (int k = 0; k < 16; ++k){
                unsigned hh = hist[tid * 16 + k];
                if (rA < c + hh){ s_dA = tid * 16 + k; s_cloA = c; break; }
                c += hh;
            }
        }
        if (rB >= plo && rB < phi){
            unsigned c = plo;
            for (int k = 0; k < 16; ++k){
                unsigned hh = hist[tid * 16 + k];
                if (rB < c + hh){ s_dB = tid * 16 + k; s_cloB = c; break; }
                c += hh;
            }
        }
        __syncthreads();
        unsigned dA = s_dA, dB = s_dB;
        if (dA != dB){
            unsigned locA = 0u, locB = 0xFFFFFFFFu;
            #pragma unroll 4
            for (int k = 0; k < 16; ++k){
                float4 v = xp4[tid + k * 256];
                unsigned kk[4] = {f2key(v.x), f2key(v.y), f2key(v.z), f2key(v.w)};
                #pragma unroll
                for (int e = 0; e < 4; ++e){
                    unsigned d = kk[e] >> 20;
                    if (d == dA) locA = max(locA, kk[e]);
                    if (d == dB) locB = min(locB, kk[e]);
                }
            }
            reduce_maxmin(locA, locB, tid, redA, redB, &s_keyA, &s_keyB);
            done = true;
        } else {
            prefVal = dA << 20; prefMask = 0xFFFu << 20;
            rA -= s_cloA; rB -= s_cloB;
            #pragma unroll 4
            for (int k = 0; k < 16; ++k){
                float4 v = xp4[tid + k * 256];
                unsigned kk[4] = {f2key(v.x), f2key(v.y), f2key(v.z), f2key(v.w)};
                #pragma unroll
                for (int e = 0; e < 4; ++e){
                    if ((kk[e] >> 20) == dA){
                        unsigned id2 = atomicAdd(&s_cnt, 1u);
                        if (id2 < SEL_CAP) cand[id2] = kk[e];
                    }
                }
            }
            __syncthreads();
        }
    }

    // ---- levels 1..3: 8,8,4 bits over candidate list ----
    if (!done){
        unsigned nc = s_cnt;
        bool useCand = (nc <= SEL_CAP);
        const int shifts[3] = {12, 4, 0};
        const int bitsv[3]  = {8, 8, 4};
        for (int lvl = 0; lvl < 3 && !done; ++lvl){
            int shift = shifts[lvl];
            unsigned nb = 1u << bitsv[lvl];
            unsigned msk = nb - 1u;
            if (tid < (int)nb) hist[tid] = 0u;
            __syncthreads();
            if (useCand){
                for (unsigned i = tid; i < nc; i += 256){
                    unsigned key = cand[i];
                    if ((key & prefMask) == prefVal)
                        atomicAdd(&hist[(key >> shift) & msk], 1u);
                }
            } else {
                #pragma unroll 4
                for (int k = 0; k < 16; ++k){
                    float4 v = xp4[tid + k * 256];
                    unsigned kk[4] = {f2key(v.x), f2key(v.y), f2key(v.z), f2key(v.w)};
                    #pragma unroll
                    for (int e = 0; e < 4; ++e)
                        if ((kk[e] & prefMask) == prefVal)
                            atomicAdd(&hist[(kk[e] >> shift) & msk], 1u);
                }
            }
            __syncthreads();
            spart[tid] = (tid < (int)nb) ? hist[tid] : 0u;
            __syncthreads();
            for (int off = 1; off < 256; off <<= 1){
                unsigned v = (tid >= off) ? spart[tid - off] : 0u;
                __syncthreads();
                spart[tid] += v;
                __syncthreads();
            }
            unsigned plo = (tid == 0) ? 0u : spart[tid - 1];
            unsigned phi = spart[tid];
            if (tid < (int)nb){
                if (rA >= plo && rA < phi){ s_dA = tid; s_cloA = plo; }
                if (rB >= plo && rB < phi){ s_dB = tid; s_cloB = plo; }
            }
            __syncthreads();
            unsigned dA = s_dA, dB = s_dB;
            if (dA != dB){
                unsigned mA = prefMask | (msk << shift);
                unsigned vAp = prefVal | (dA << shift);
                unsigned vBp = prefVal | (dB << shift);
                unsigned locA = 0u, locB = 0xFFFFFFFFu;
                if (useCand){
                    for (unsigned i = tid; i < nc; i += 256){
                        unsigned key = cand[i];
                        if ((key & mA) == vAp) locA = max(locA, key);
                        if ((key & mA) == vBp) locB = min(locB, key);
                    }
                } else {
                    #pragma unroll 4
                    for (int k = 0; k < 16; ++k){
                        float4 v = xp4[tid + k * 256];
                        unsigned kk[4] = {f2key(v.x), f2key(v.y), f2key(v.z), f2key(v.w)};
                        #pragma unroll
                        for (int e = 0; e < 4; ++e){
                            if ((kk[e] & mA) == vAp) locA = max(locA, kk[e]);
                            if ((kk[e] & mA) == vBp) locB = min(locB, kk[e]);
                        }
                    }
                }
                reduce_maxmin(locA, locB, tid, redA, redB, &s_keyA, &s_keyB);
                done = true;
            } else {
                prefVal |= dA << shift;
                prefMask |= msk << shift;
                rA -= s_cloA; rB -= s_cloB;
                if (lvl == 2){
                    if (tid == 0){ s_keyA = prefVal; s_keyB = prefVal; }
                    done = true;
                }
                __syncthreads();
            }
        }
    }

    if (tid == 0){
        float vlo = key2f(s_keyA);
        float vhi = key2f(s_keyB);
        float idxq = 0.95f * 16383.0f;
        float frac = idxq - floorf(idxq);
        throut[bc] = vlo * (1.0f - frac) + vhi * frac;
    }
}

// K1b: tiled mask + pools. 16 output rows per block, 3-row halo.
// LDS ~36KB -> 4 blocks/CU. Writes outp (full res) and d1 (64x64 grid).
__global__ __launch_bounds__(256) void k1b_prop(
    const float* __restrict__ x, const float* __restrict__ thrbuf,
    float* __restrict__ outp, float* __restrict__ d1g, float g1)
{
    __shared__ __align__(16) float C0[21 * 128];
    __shared__ __align__(16) float A [21 * 128];
    __shared__ __align__(16) float A1[19 * 128];
    __shared__ __align__(16) float H5[19 * 64];

    const int tid = threadIdx.x;
    const unsigned blk = blockIdx.x;
    const unsigned bc = blk >> 3;
    const int r0 = (int)(blk & 7u) * 16;
    const int base0 = r0 - 3;           // abs row of C0/A local row 0
    // A1/H5 local row 0 is abs row r0-2

    const float thr = thrbuf[bc];
    const float4* xp4 = (const float4*)(x + (size_t)bc * HW_);

    // load 21 rows of x, mask -> C0; out-of-range rows = -FLT_MAX
    for (int i = tid; i < 21 * 32; i += 256){
        int la = i >> 5, c4 = i & 31;
        int r = base0 + la;
        float4 v;
        if (r >= 0 && r < 128){
            v = xp4[r * 32 + c4];
            v.x = (v.x >= thr) ? v.x : 0.0f;
            v.y = (v.y >= thr) ? v.y : 0.0f;
            v.z = (v.z >= thr) ? v.z : 0.0f;
            v.w = (v.w >= thr) ? v.w : 0.0f;
        } else {
            v.x = v.y = v.z = v.w = -FLT_MAX;
        }
        ((float4*)C0)[i] = v;
    }
    __syncthreads();

    // horizontal rowmax3 -> A (21 rows)
    for (int i = tid; i < 21 * 128; i += 256){
        int j = i & 127;
        float m = C0[i];
        if (j > 0)   m = fmaxf(m, C0[i - 1]);
        if (j < 127) m = fmaxf(m, C0[i + 1]);
        A[i] = m;
    }
    __syncthreads();

    // vertical colmax3 * 0.99 -> A1 (19 rows, abs r0-2..r0+16)
    for (int i = tid; i < 19 * 128; i += 256){
        int la1 = i >> 7, j = i & 127;
        int ar = la1 + 1;              // A local row for same abs row
        float m = A[ar * 128 + j];
        m = fmaxf(m, A[(ar - 1) * 128 + j]);
        m = fmaxf(m, A[(ar + 1) * 128 + j]);
        A1[i] = 0.99f * m;
    }
    __syncthreads();

    // outp = max(c0, a1) for the 16 output rows
    {
        float* op = outp + (size_t)bc * HW_;
        for (int i = tid; i < 16 * 32; i += 256){
            int lo = i >> 5, c4 = i & 31;
            float4 c0v = ((const float4*)C0)[(lo + 3) * 32 + c4];
            float4 a1v = ((const float4*)A1)[(lo + 2) * 32 + c4];
            float4 o;
            o.x = fmaxf(c0v.x, a1v.x);
            o.y = fmaxf(c0v.y, a1v.y);
            o.z = fmaxf(c0v.z, a1v.z);
            o.w = fmaxf(c0v.w, a1v.w);
            ((float4*)op)[(r0 + lo) * 32 + c4] = o;
        }
    }

    // horizontal 5-tap at even centers over A1 -> H5 (19 rows x 64)
    for (int i = tid; i < 19 * 64; i += 256){
        int lr = i >> 6, ci = i & 63;
        int c = 2 * ci;
        const float* row = A1 + lr * 128;
        float m = fmaxf(row[c], row[c + 1]);
        if (ci > 0)  m = fmaxf(m, fmaxf(row[c - 1], row[c - 2]));
        if (ci < 63) m = fmaxf(m, row[c + 2]);
        H5[i] = m;
    }
    __syncthreads();

    // vertical 5-tap stride-2 + scale -> d1 rows r0/2 .. r0/2+7
    {
        float* dp = d1g + (size_t)bc * 4096;
        for (int i = tid; i < 8 * 64; i += 256){
            int li = i >> 6, j = i & 63;
            int lr = 2 * li;           // H5 local row of abs row 2*di - 2
            float m = H5[lr * 64 + j];
            m = fmaxf(m, H5[(lr + 1) * 64 + j]);
            m = fmaxf(m, H5[(lr + 2) * 64 + j]);
            m = fmaxf(m, H5[(lr + 3) * 64 + j]);
            m = fmaxf(m, H5[(lr + 4) * 64 + j]);
            dp[(r0 / 2 + li) * 64 + j] = g1 * m;
        }
    }
}

// K2: 64x64 chain d2..d5, m64 = max(d1..d5), in-place over d1 buffer
__global__ __launch_bounds__(256) void k2_chain(
    float* __restrict__ dm, float g2, float g3, float g4, float g5)
{
    __shared__ __align__(16) float D[4096];
    __shared__ __align__(16) float T[4096];
    __shared__ __align__(16) float M[4096];
    const int tid = threadIdx.x;
    const unsigned bc = blockIdx.x;
    float* p = dm + (size_t)bc * 4096;
    const float4* p4 = (const float4*)p;
    #pragma unroll
    for (int k = 0; k < 4; ++k){
        float4 v = p4[tid + k * 256];
        ((float4*)D)[tid + k * 256] = v;
        ((float4*)M)[tid + k * 256] = v;
    }
    __syncthreads();
    const float gs[4] = {g2, g3, g4, g5};
    for (int it = 0; it < 4; ++it){
        float g = gs[it];
        #pragma unroll 4
        for (int k = 0; k < 16; ++k){
            int q = tid + k * 256;
            int j = q & 63;
            float m = D[q];
            if (j > 0)  m = fmaxf(m, D[q - 1]);
            if (j < 63) m = fmaxf(m, D[q + 1]);
            T[q] = m;
        }
        __syncthreads();
        #pragma unroll 4
        for (int k = 0; k < 16; ++k){
            int q = tid + k * 256;
            int r = q >> 6;
            float m = T[q];
            if (r > 0)  m = fmaxf(m, T[q - 64]);
            if (r < 63) m = fmaxf(m, T[q + 64]);
            float v = g * m;
            D[q] = v;
            M[q] = fmaxf(M[q], v);
        }
        __syncthreads();
    }
    #pragma unroll
    for (int k = 0; k < 4; ++k)
        ((float4*)p)[tid + k * 256] = ((float4*)M)[tid + k * 256];
}

// K3: fused  out' = max(outp, up(m64)) -> h = relu(W1 out'+b1) ->
//            R = sigmoid(W2 h + b2) -> y = x*R
__global__ __launch_bounds__(256) void k3_mlp(
    const float* __restrict__ x, const float* __restrict__ outp,
    const float* __restrict__ m64,
    const float* __restrict__ w1, const float* __restrict__ b1,
    const float* __restrict__ w2, const float* __restrict__ b2,
    float* __restrict__ y)
{
    __shared__ __align__(16) float W1s[256 * 16];  // [c][m]
    __shared__ __align__(16) float W2s[256 * 16];  // [c][m]
    __shared__ float B1s[16];
    __shared__ float B2s[256];
    const int tid = threadIdx.x;
    const int blk = blockIdx.x;
    const int b = blk >> 6;
    const int t = blk & 63;

    for (int q = tid; q < 4096; q += 256){
        int c = q >> 4, m = q & 15;
        W1s[q] = w1[m * 256 + c];
        W2s[q] = w2[q];
    }
    if (tid < 16) B1s[tid] = b1[tid];
    B2s[tid] = b2[tid];
    __syncthreads();

    const int pix = t * 256 + tid;
    const int mi = (pix >> 8) * 64 + ((pix & 127) >> 1);
    const size_t base = (size_t)b * 256 * HW_;
    const size_t mbase = (size_t)b * 256 * 4096;

    float h[16];
    #pragma unroll
    for (int m = 0; m < 16; ++m) h[m] = 0.0f;

    #pragma unroll 4
    for (int c = 0; c < 256; ++c){
        float o  = outp[base + (size_t)c * HW_ + pix];
        float mo = m64[mbase + (size_t)c * 4096 + mi];
        o = fmaxf(o, mo);
        const float4* wr = (const float4*)&W1s[c * 16];
        float4 a0 = wr[0], a1 = wr[1], a2 = wr[2], a3 = wr[3];
        h[0]  = fmaf(a0.x, o, h[0]);  h[1]  = fmaf(a0.y, o, h[1]);
        h[2]  = fmaf(a0.z, o, h[2]);  h[3]  = fmaf(a0.w, o, h[3]);
        h[4]  = fmaf(a1.x, o, h[4]);  h[5]  = fmaf(a1.y, o, h[5]);
        h[6]  = fmaf(a1.z, o, h[6]);  h[7]  = fmaf(a1.w, o, h[7]);
        h[8]  = fmaf(a2.x, o, h[8]);  h[9]  = fmaf(a2.y, o, h[9]);
        h[10] = fmaf(a2.z, o, h[10]); h[11] = fmaf(a2.w, o, h[11]);
        h[12] = fmaf(a3.x, o, h[12]); h[13] = fmaf(a3.y, o, h[13]);
        h[14] = fmaf(a3.z, o, h[14]); h[15] = fmaf(a3.w, o, h[15]);
    }
    #pragma unroll
    for (int m = 0; m < 16; ++m) h[m] = fmaxf(h[m] + B1s[m], 0.0f);

    #pragma unroll 4
    for (int c = 0; c < 256; ++c){
        const float4* wr = (const float4*)&W2s[c * 16];
        float4 a0 = wr[0], a1 = wr[1], a2 = wr[2], a3 = wr[3];
        float acc = B2s[c];
        acc += a0.x * h[0]  + a0.y * h[1]  + a0.z * h[2]  + a0.w * h[3];
        acc += a1.x * h[4]  + a1.y * h[5]  + a1.z * h[6]  + a1.w * h[7];
        acc += a2.x * h[8]  + a2.y * h[9]  + a2.z * h[10] + a2.w * h[11];
        acc += a3.x * h[12] + a3.y * h[13] + a3.z * h[14] + a3.w * h[15];
        float R = 1.0f / (1.0f + __expf(-acc));
        float xv = x[base + (size_t)c * HW_ + pix];
        y[base + (size_t)c * HW_ + pix] = xv * R;
    }
}

extern "C" void kernel_launch(void* const* d_in, const int* in_sizes, int n_in,
                              void* d_out, int out_size, void* d_ws, size_t ws_size,
                              hipStream_t stream) {
    const float* x  = (const float*)d_in[0];
    const float* w1 = (const float*)d_in[1];
    const float* b1 = (const float*)d_in[2];
    const float* w2 = (const float*)d_in[3];
    const float* b2 = (const float*)d_in[4];
    float* y  = (float*)d_out;
    float* ws = (float*)d_ws;

    float* outp = ws;                          // 67108864 floats (268 MB)
    float* d1   = ws + 67108864;               // 16777216 floats (67 MB), reused as m64
    float* thrb = ws + 67108864 + 16777216;    // 4096 floats

    float g[6];
    for (int i = 0; i < 6; ++i) g[i] = (float)std::pow(0.99, (double)(1 << i));

    k1a_thr <<<4096, 256, 0, stream>>>(x, thrb);
    k1b_prop<<<32768, 256, 0, stream>>>(x, thrb, outp, d1, g[1]);
    k2_chain<<<4096, 256, 0, stream>>>(d1, g[2], g[3], g[4], g[5]);
    k3_mlp  <<<1024, 256, 0, stream>>>(x, outp, d1, w1, b1, w2, b2, y);
}